// Round 1
// baseline (9417.150 us; speedup 1.0000x reference)
//
#include <hip/hip_runtime.h>

#define T_STEPS 128
#define VSZ 512
#define FULLSZ 1024

#define BM 64
#define BN 64
#define BK 32
#define PAD 4  // LDS row pad (floats) to break bank conflicts; keeps 16B alignment

// t=0: R = relu(U0), U0[i][j] = Lam(i,j)*b[j] + (j<V && i!=j ? 0.5*x0[j] : 0)
// Lam(i,j) = (j<V) ? (i==j ? 1 : 0.5) : 1
__global__ void rnn_init_kernel(const float* __restrict__ X,
                                const float* __restrict__ b,
                                float* __restrict__ R0) {
    int idx = blockIdx.x * 256 + threadIdx.x;           // 0 .. 512*1024-1
    int i = idx >> 10;
    int j = idx & 1023;
    float bj = b[j];
    float u;
    if (j >= VSZ)      u = bj;
    else if (i == j)   u = bj;
    else               u = 0.5f * bj + 0.5f * X[j];     // x_0 = X row 0
    R0[idx] = fmaxf(u, 0.0f);
}

// One recurrent step: Rout = relu( Lam * (Rin @ W^T + b) + mask * x_t )
// Tiled fp32 GEMM: C[i][j] = sum_k Rin[i][k] * W[j][k]
__global__ __launch_bounds__(256)
void rnn_step_kernel(const float* __restrict__ Rin,
                     float* __restrict__ Rout,
                     const float* __restrict__ W,
                     const float* __restrict__ b,
                     const float* __restrict__ x) {
    __shared__ float As[BK][BM + PAD];   // transposed: As[k][i]
    __shared__ float Bs[BK][BN + PAD];   // transposed: Bs[k][j]

    const int i0 = blockIdx.x * BM;      // 8 tiles over M=512
    const int j0 = blockIdx.y * BN;      // 16 tiles over N=1024
    const int tid = threadIdx.x;
    const int ty = tid >> 4;             // 0..15 -> output rows ty*4..+3
    const int tx = tid & 15;             // 0..15 -> output cols tx*4..+3

    float acc[4][4];
#pragma unroll
    for (int m = 0; m < 4; ++m)
#pragma unroll
        for (int n = 0; n < 4; ++n) acc[m][n] = 0.0f;

    for (int kb = 0; kb < FULLSZ; kb += BK) {
        // Stage A (Rin rows i0..i0+63, cols kb..kb+31) and B (W rows j0..j0+63)
        // 64 rows x 8 float4 = 512 float4 each; 256 threads -> 2 each.
#pragma unroll
        for (int s = 0; s < 2; ++s) {
            int idx = tid + s * 256;
            int r = idx >> 3;            // 0..63
            int q = idx & 7;             // 0..7
            float4 va = *reinterpret_cast<const float4*>(&Rin[(i0 + r) * FULLSZ + kb + q * 4]);
            As[q * 4 + 0][r] = va.x;
            As[q * 4 + 1][r] = va.y;
            As[q * 4 + 2][r] = va.z;
            As[q * 4 + 3][r] = va.w;
            float4 vb = *reinterpret_cast<const float4*>(&W[(j0 + r) * FULLSZ + kb + q * 4]);
            Bs[q * 4 + 0][r] = vb.x;
            Bs[q * 4 + 1][r] = vb.y;
            Bs[q * 4 + 2][r] = vb.z;
            Bs[q * 4 + 3][r] = vb.w;
        }
        __syncthreads();

#pragma unroll 8
        for (int k = 0; k < BK; ++k) {
            float4 a = *reinterpret_cast<const float4*>(&As[k][ty * 4]);
            float4 bv = *reinterpret_cast<const float4*>(&Bs[k][tx * 4]);
            acc[0][0] += a.x * bv.x; acc[0][1] += a.x * bv.y; acc[0][2] += a.x * bv.z; acc[0][3] += a.x * bv.w;
            acc[1][0] += a.y * bv.x; acc[1][1] += a.y * bv.y; acc[1][2] += a.y * bv.z; acc[1][3] += a.y * bv.w;
            acc[2][0] += a.z * bv.x; acc[2][1] += a.z * bv.y; acc[2][2] += a.z * bv.z; acc[2][3] += a.z * bv.w;
            acc[3][0] += a.w * bv.x; acc[3][1] += a.w * bv.y; acc[3][2] += a.w * bv.z; acc[3][3] += a.w * bv.w;
        }
        __syncthreads();
    }

    // Epilogue: mask + x add + relu
#pragma unroll
    for (int m = 0; m < 4; ++m) {
        int i = i0 + ty * 4 + m;
#pragma unroll
        for (int n = 0; n < 4; ++n) {
            int j = j0 + tx * 4 + n;
            float wr = acc[m][n] + b[j];
            float u;
            if (j >= VSZ)      u = wr;          // Lam = 1
            else if (i == j)   u = wr;          // Lam = 1, one_minus = 0
            else               u = 0.5f * wr + 0.5f * x[j];
            Rout[i * FULLSZ + j] = fmaxf(u, 0.0f);
        }
    }
}

// Final: out[i] = dot(R126[i,:], W[i,:]) + b[i]   (diagonal of U_127[:, :V])
__global__ void rnn_diag_kernel(const float* __restrict__ R,
                                const float* __restrict__ W,
                                const float* __restrict__ b,
                                float* __restrict__ out) {
    int i = blockIdx.x;          // 0..511
    int lane = threadIdx.x;      // 0..63
    const float4* r4 = reinterpret_cast<const float4*>(R + i * FULLSZ);
    const float4* w4 = reinterpret_cast<const float4*>(W + i * FULLSZ);
    float s = 0.0f;
#pragma unroll
    for (int c = lane; c < FULLSZ / 4; c += 64) {
        float4 a = r4[c];
        float4 w = w4[c];
        s += a.x * w.x + a.y * w.y + a.z * w.z + a.w * w.w;
    }
#pragma unroll
    for (int off = 32; off > 0; off >>= 1) s += __shfl_down(s, off);
    if (lane == 0) out[i] = s + b[i];
}

extern "C" void kernel_launch(void* const* d_in, const int* in_sizes, int n_in,
                              void* d_out, int out_size, void* d_ws, size_t ws_size,
                              hipStream_t stream) {
    const float* X = (const float*)d_in[0];   // (128, 512)
    const float* W = (const float*)d_in[1];   // (1024, 1024)
    const float* b = (const float*)d_in[2];   // (1024,)
    float* out = (float*)d_out;               // (512,)

    float* Rbuf0 = (float*)d_ws;                       // 512*1024 fp32 = 2 MB
    float* Rbuf1 = Rbuf0 + (size_t)VSZ * FULLSZ;       // next 2 MB
    float* bufs[2] = {Rbuf0, Rbuf1};

    // t = 0 (R == 0 -> WR = b broadcast)
    rnn_init_kernel<<<(VSZ * FULLSZ) / 256, 256, 0, stream>>>(X, b, Rbuf0);

    // t = 1 .. 126: full GEMM steps, ping-pong R buffers
    dim3 grid(VSZ / BM, FULLSZ / BN);  // (8, 16)
    for (int t = 1; t <= T_STEPS - 2; ++t) {
        const float* Rin = bufs[(t - 1) & 1];
        float* Rout = bufs[t & 1];
        rnn_step_kernel<<<grid, 256, 0, stream>>>(Rin, Rout, W, b, X + (size_t)t * VSZ);
    }

    // t = 127: only the diagonal of U is needed (R126 lives in bufs[0])
    rnn_diag_kernel<<<VSZ, 64, 0, stream>>>(bufs[(T_STEPS - 2) & 1], W, b, out);
}

// Round 2
// 4322.003 us; speedup vs baseline: 2.1789x; 2.1789x over previous
//
#include <hip/hip_runtime.h>

#define T_STEPS 128
#define VSZ 512
#define FULLSZ 1024

#define BM 32
#define BN 64
#define BK 32
#define NKB (FULLSZ / BK)   // 32 k-blocks

// t=0: R = relu(U0), U0[i][j] = Lam(i,j)*b[j] + (j<V && i!=j ? 0.5*x0[j] : 0)
__global__ void rnn_init_kernel(const float* __restrict__ X,
                                const float* __restrict__ b,
                                float* __restrict__ R0) {
    int idx = blockIdx.x * 256 + threadIdx.x;
    int i = idx >> 10;
    int j = idx & 1023;
    float bj = b[j];
    float u;
    if (j >= VSZ)      u = bj;
    else if (i == j)   u = bj;
    else               u = 0.5f * bj + 0.5f * X[j];
    R0[idx] = fmaxf(u, 0.0f);
}

// One step: Rout = relu( Lam * (Rin @ W^T + b) + mask * x_t )
// C[i][j] = sum_k Rin[i][k] * W[j][k]
// 32x64 tile, 256 threads, 2x4 per thread, reg->LDS double buffer.
__global__ __launch_bounds__(256, 1)
void rnn_step_kernel(const float* __restrict__ Rin,
                     float* __restrict__ Rout,
                     const float* __restrict__ W,
                     const float* __restrict__ b,
                     const float* __restrict__ x) {
    __shared__ float As[2][BK][BM + 2];   // [buf][k][i], stride 34 (float2-aligned)
    __shared__ float Bs[2][BK][BN + 4];   // [buf][k][j], stride 68 (float4-aligned)

    const int i0 = blockIdx.x * BM;       // 16 tiles over M=512
    const int j0 = blockIdx.y * BN;       // 16 tiles over N=1024
    const int tid = threadIdx.x;
    const int ty = tid >> 4;              // 0..15 -> rows ty*2 + {0,1}
    const int tx = tid & 15;              // 0..15 -> cols tx*4 + {0..3}

    const int ra = tid >> 3;              // 0..31
    const int qa = tid & 7;               // 0..7
    const int rb1 = ra + 32;              // 32..63

    const float4* Arow  = reinterpret_cast<const float4*>(Rin + (size_t)(i0 + ra) * FULLSZ);
    const float4* Brow0 = reinterpret_cast<const float4*>(W + (size_t)(j0 + ra) * FULLSZ);
    const float4* Brow1 = reinterpret_cast<const float4*>(W + (size_t)(j0 + rb1) * FULLSZ);

    float4 pa, pb0, pb1;
    pa  = Arow[qa];
    pb0 = Brow0[qa];
    pb1 = Brow1[qa];

    float acc[2][4] = {{0.f, 0.f, 0.f, 0.f}, {0.f, 0.f, 0.f, 0.f}};

#define STORE_TILES(bufi) do {                      \
        As[bufi][qa * 4 + 0][ra] = pa.x;            \
        As[bufi][qa * 4 + 1][ra] = pa.y;            \
        As[bufi][qa * 4 + 2][ra] = pa.z;            \
        As[bufi][qa * 4 + 3][ra] = pa.w;            \
        Bs[bufi][qa * 4 + 0][ra] = pb0.x;           \
        Bs[bufi][qa * 4 + 1][ra] = pb0.y;           \
        Bs[bufi][qa * 4 + 2][ra] = pb0.z;           \
        Bs[bufi][qa * 4 + 3][ra] = pb0.w;           \
        Bs[bufi][qa * 4 + 0][rb1] = pb1.x;          \
        Bs[bufi][qa * 4 + 1][rb1] = pb1.y;          \
        Bs[bufi][qa * 4 + 2][rb1] = pb1.z;          \
        Bs[bufi][qa * 4 + 3][rb1] = pb1.w;          \
    } while (0)

    STORE_TILES(0);
    __syncthreads();

    for (int kb = 0; kb < NKB; ++kb) {
        const int c = kb & 1;
        if (kb + 1 < NKB) {
            pa  = Arow[(kb + 1) * 8 + qa];
            pb0 = Brow0[(kb + 1) * 8 + qa];
            pb1 = Brow1[(kb + 1) * 8 + qa];
        }
#pragma unroll
        for (int k = 0; k < BK; ++k) {
            float2 a  = *reinterpret_cast<const float2*>(&As[c][k][ty * 2]);
            float4 bb = *reinterpret_cast<const float4*>(&Bs[c][k][tx * 4]);
            acc[0][0] += a.x * bb.x; acc[0][1] += a.x * bb.y;
            acc[0][2] += a.x * bb.z; acc[0][3] += a.x * bb.w;
            acc[1][0] += a.y * bb.x; acc[1][1] += a.y * bb.y;
            acc[1][2] += a.y * bb.z; acc[1][3] += a.y * bb.w;
        }
        if (kb + 1 < NKB) {
            STORE_TILES((kb + 1) & 1);
            __syncthreads();
        }
    }
#undef STORE_TILES

    // Epilogue: mask + x add + relu, float4 stores
    const int jb = j0 + tx * 4;
    float4 b4 = *reinterpret_cast<const float4*>(&b[jb]);
    float4 x4 = make_float4(0.f, 0.f, 0.f, 0.f);
    if (jb < VSZ) x4 = *reinterpret_cast<const float4*>(&x[jb]);

#pragma unroll
    for (int m = 0; m < 2; ++m) {
        int i = i0 + ty * 2 + m;
        float wr0 = acc[m][0] + b4.x;
        float wr1 = acc[m][1] + b4.y;
        float wr2 = acc[m][2] + b4.z;
        float wr3 = acc[m][3] + b4.w;
        float4 u;
        if (jb >= VSZ) {
            u = make_float4(wr0, wr1, wr2, wr3);
        } else {
            u.x = (i == jb + 0) ? wr0 : 0.5f * wr0 + 0.5f * x4.x;
            u.y = (i == jb + 1) ? wr1 : 0.5f * wr1 + 0.5f * x4.y;
            u.z = (i == jb + 2) ? wr2 : 0.5f * wr2 + 0.5f * x4.z;
            u.w = (i == jb + 3) ? wr3 : 0.5f * wr3 + 0.5f * x4.w;
        }
        u.x = fmaxf(u.x, 0.f); u.y = fmaxf(u.y, 0.f);
        u.z = fmaxf(u.z, 0.f); u.w = fmaxf(u.w, 0.f);
        *reinterpret_cast<float4*>(&Rout[(size_t)i * FULLSZ + jb]) = u;
    }
}

// Final: out[i] = dot(R126[i,:], W[i,:]) + b[i]
__global__ void rnn_diag_kernel(const float* __restrict__ R,
                                const float* __restrict__ W,
                                const float* __restrict__ b,
                                float* __restrict__ out) {
    int i = blockIdx.x;
    int lane = threadIdx.x;
    const float4* r4 = reinterpret_cast<const float4*>(R + (size_t)i * FULLSZ);
    const float4* w4 = reinterpret_cast<const float4*>(W + (size_t)i * FULLSZ);
    float s = 0.0f;
#pragma unroll
    for (int c = lane; c < FULLSZ / 4; c += 64) {
        float4 a = r4[c];
        float4 w = w4[c];
        s += a.x * w.x + a.y * w.y + a.z * w.z + a.w * w.w;
    }
#pragma unroll
    for (int off = 32; off > 0; off >>= 1) s += __shfl_down(s, off);
    if (lane == 0) out[i] = s + b[i];
}

extern "C" void kernel_launch(void* const* d_in, const int* in_sizes, int n_in,
                              void* d_out, int out_size, void* d_ws, size_t ws_size,
                              hipStream_t stream) {
    const float* X = (const float*)d_in[0];   // (128, 512)
    const float* W = (const float*)d_in[1];   // (1024, 1024)
    const float* b = (const float*)d_in[2];   // (1024,)
    float* out = (float*)d_out;               // (512,)

    float* Rbuf0 = (float*)d_ws;
    float* Rbuf1 = Rbuf0 + (size_t)VSZ * FULLSZ;
    float* bufs[2] = {Rbuf0, Rbuf1};

    rnn_init_kernel<<<(VSZ * FULLSZ) / 256, 256, 0, stream>>>(X, b, Rbuf0);

    dim3 grid(VSZ / BM, FULLSZ / BN);  // (16, 16) = 256 blocks
    for (int t = 1; t <= T_STEPS - 2; ++t) {
        const float* Rin = bufs[(t - 1) & 1];
        float* Rout = bufs[t & 1];
        rnn_step_kernel<<<grid, 256, 0, stream>>>(Rin, Rout, W, b, X + (size_t)t * VSZ);
    }

    rnn_diag_kernel<<<VSZ, 64, 0, stream>>>(bufs[(T_STEPS - 2) & 1], W, b, out);
}

// Round 3
// 3157.296 us; speedup vs baseline: 2.9827x; 1.3689x over previous
//
#include <hip/hip_runtime.h>
#include <stdint.h>

#define Vv 512
#define Ff 1024

typedef unsigned short u16;
typedef __attribute__((ext_vector_type(8))) short s16x8;
typedef __attribute__((ext_vector_type(4))) float f32x4;

// Exact 3-way bf16 truncation split: v == h + m + l (bit-exact, 24 mantissa bits)
__device__ __forceinline__ void split3(float v, u16& h, u16& m, u16& l) {
    unsigned u = __float_as_uint(v);
    float fh = __uint_as_float(u & 0xFFFF0000u);
    h = (u16)(u >> 16);
    float r1 = v - fh;                         // exact
    unsigned u1 = __float_as_uint(r1);
    float fm = __uint_as_float(u1 & 0xFFFF0000u);
    m = (u16)(u1 >> 16);
    float r2 = r1 - fm;                        // exact
    l = (u16)(__float_as_uint(r2) >> 16);
}

__global__ void wsplit_kernel(const float* __restrict__ W,
                              u16* __restrict__ Wh, u16* __restrict__ Wm, u16* __restrict__ Wl) {
    int idx = blockIdx.x * 256 + threadIdx.x;   // 0 .. 1M-1
    float w = W[idx];
    u16 h, m, l; split3(w, h, m, l);
    Wh[idx] = h; Wm[idx] = m; Wl[idx] = l;
}

// t=0: R0 = relu(U0); U0[i][j] = b[j] (j>=V or i==j) else 0.5*b[j]+0.5*x0[j]
__global__ void init_kernel(const float* __restrict__ X, const float* __restrict__ b,
                            u16* __restrict__ Rh, u16* __restrict__ Rm, u16* __restrict__ Rl) {
    int idx = blockIdx.x * 256 + threadIdx.x;   // 0 .. 512K-1
    int i = idx >> 10, j = idx & 1023;
    float u = b[j];
    if (j < Vv && i != j) u = 0.5f * u + 0.5f * X[j];
    u = fmaxf(u, 0.f);
    u16 h, m, l; split3(u, h, m, l);
    Rh[idx] = h; Rm[idx] = m; Rl[idx] = l;
}

// One step: O = relu(Lam*(R@W^T + b) + mask*x), R,W as exact bf16 triplets.
// Tile 32x64 per block, grid 256 (1 block/CU), 4 waves (2m x 2n), BK=64.
// 6-product scheme: hh + hm + mh + hl + lh + mm  (all terms >= 2^-24 kept).
__global__ __launch_bounds__(256, 1)
void step_kernel(const u16* __restrict__ Rh, const u16* __restrict__ Rm, const u16* __restrict__ Rl,
                 const u16* __restrict__ Wh, const u16* __restrict__ Wm, const u16* __restrict__ Wl,
                 u16* __restrict__ Oh, u16* __restrict__ Om, u16* __restrict__ Ol,
                 const float* __restrict__ b, const float* __restrict__ x) {
    // Per buffer (36864 B): A levels at lv*4096 (32r x 64k bf16, k-major 16B units:
    // unit L = s*32 + r); B levels at 12288 + lv*8192 (64r: L = s*64 + r).
    // Bank phase = L mod 8 = r mod 8 -> uniform, optimal 4-phase ds_read_b128.
    __shared__ unsigned char smem[2 * 36864];

    const int tid = threadIdx.x;
    const int bid = blockIdx.x;
    const int rb = (bid & 7) * 32 + (bid >> 3);   // XCD-chunked swizzle (bijective, 256%8==0)
    const int i0 = (rb & 15) * 32;
    const int j0 = (rb >> 4) * 64;

    // ---- staging descriptors: 9 x 16B per thread per k-chunk (2304 units) ----
    const u16* gb[9]; unsigned lo[9];
    const u16* Rlv[3] = {Rh, Rm, Rl};
    const u16* Wlv[3] = {Wh, Wm, Wl};
#pragma unroll
    for (int q = 0; q < 9; ++q) {
        int G = q * 256 + tid;
        if (G < 768) {                    // A: 3 levels x 256 units
            int lv = G >> 8, L = G & 255, s = L >> 5, r = L & 31;
            gb[q] = Rlv[lv] + (i0 + r) * Ff + s * 8;
            lo[q] = (unsigned)(lv * 4096 + L * 16);
        } else {                          // B: 3 levels x 512 units
            int Gp = G - 768;
            int lv = Gp >> 9, L = Gp & 511, s = L >> 6, r = L & 63;
            gb[q] = Wlv[lv] + (j0 + r) * Ff + s * 8;
            lo[q] = (unsigned)(12288 + lv * 8192 + L * 16);
        }
    }

    const int lane = tid & 63;
    const int l15 = lane & 15, l4 = lane >> 4;
    const int w = tid >> 6;
    const int mh = w >> 1, nh = w & 1;    // wave -> (m-half, n-half)
    const unsigned aoff0 = (unsigned)((l4 * 32 + mh * 16 + l15) * 16);
    const unsigned boff0 = (unsigned)(12288 + (l4 * 64 + nh * 32 + l15) * 16);

    f32x4 acc[2][2];   // [nf][kf] -- 4 independent MFMA chains
#pragma unroll
    for (int a = 0; a < 2; ++a)
#pragma unroll
        for (int c = 0; c < 2; ++c) acc[a][c] = (f32x4){0.f, 0.f, 0.f, 0.f};

#define STAGE(buf, kb) do {                                                          \
        unsigned bofs_ = (unsigned)(buf) * 36864u;                                   \
        _Pragma("unroll")                                                            \
        for (int q_ = 0; q_ < 9; ++q_)                                               \
            __builtin_amdgcn_global_load_lds(                                        \
                (const __attribute__((address_space(1))) void*)(gb[q_] + (kb) * 64), \
                (__attribute__((address_space(3))) void*)(smem + bofs_ + lo[q_]),    \
                16, 0, 0);                                                           \
    } while (0)

    STAGE(0, 0);
    __syncthreads();

    for (int kb = 0; kb < 16; ++kb) {
        const unsigned cb = (unsigned)(kb & 1) * 36864u;
        if (kb < 15) STAGE((kb & 1) ^ 1, kb + 1);   // async prefetch under compute

        s16x8 Af[3][2], Bf[3][2][2];
#pragma unroll
        for (int lv = 0; lv < 3; ++lv)
#pragma unroll
            for (int kf = 0; kf < 2; ++kf) {
                Af[lv][kf] = *(const s16x8*)(smem + cb + (unsigned)(lv * 4096 + kf * 2048) + aoff0);
#pragma unroll
                for (int nf = 0; nf < 2; ++nf)
                    Bf[lv][nf][kf] = *(const s16x8*)(smem + cb + (unsigned)(lv * 8192 + kf * 4096 + nf * 256) + boff0);
            }

        const int LVA[6] = {0, 0, 1, 0, 2, 1};
        const int LVB[6] = {0, 1, 0, 2, 0, 1};
#pragma unroll
        for (int p = 0; p < 6; ++p)
#pragma unroll
            for (int kf = 0; kf < 2; ++kf)
#pragma unroll
                for (int nf = 0; nf < 2; ++nf)
                    asm("v_mfma_f32_16x16x32_bf16 %0, %1, %2, %0"
                        : "+v"(acc[nf][kf])
                        : "v"(Af[LVA[p]][kf]), "v"(Bf[LVB[p]][nf][kf]));

        __syncthreads();   // drains staging (vmcnt0) + protects buffer reuse
    }
#undef STAGE

    asm volatile("s_nop 7\n\ts_nop 7");   // MFMA->VALU read hazard guard

    // Epilogue: bias + mask + relu + exact re-split, fused.
#pragma unroll
    for (int nf = 0; nf < 2; ++nf) {
        f32x4 a0 = acc[nf][0] + acc[nf][1];
        const int j = j0 + nh * 32 + nf * 16 + l15;
        const float bj = b[j];
        const float xj = (j < Vv) ? x[j] : 0.f;
#pragma unroll
        for (int p = 0; p < 4; ++p) {
            const int i = i0 + mh * 16 + l4 * 4 + p;
            float u = a0[p] + bj;
            if (j < Vv && i != j) u = 0.5f * u + 0.5f * xj;
            u = fmaxf(u, 0.f);
            u16 h, m, l; split3(u, h, m, l);
            size_t o = (size_t)i * Ff + j;
            Oh[o] = h; Om[o] = m; Ol[o] = l;
        }
    }
}

// Final: out[i] = dot(R126[i,:], W[i,:]) + b[i]; R reconstructed exactly (h+m+l).
__global__ void diag_kernel(const u16* __restrict__ Rh, const u16* __restrict__ Rm,
                            const u16* __restrict__ Rl,
                            const float* __restrict__ W, const float* __restrict__ b,
                            float* __restrict__ out) {
    int i = blockIdx.x;
    int lane = threadIdx.x;
    float s = 0.f;
    for (int c = lane; c < Ff; c += 64) {
        size_t o = (size_t)i * Ff + c;
        float r = __uint_as_float((unsigned)Rh[o] << 16)
                + __uint_as_float((unsigned)Rm[o] << 16)
                + __uint_as_float((unsigned)Rl[o] << 16);
        s += r * W[o];
    }
#pragma unroll
    for (int off = 32; off > 0; off >>= 1) s += __shfl_down(s, off);
    if (lane == 0) out[i] = s + b[i];
}

extern "C" void kernel_launch(void* const* d_in, const int* in_sizes, int n_in,
                              void* d_out, int out_size, void* d_ws, size_t ws_size,
                              hipStream_t stream) {
    const float* X = (const float*)d_in[0];   // (128, 512)
    const float* W = (const float*)d_in[1];   // (1024, 1024)
    const float* b = (const float*)d_in[2];   // (1024,)
    float* out = (float*)d_out;

    char* ws = (char*)d_ws;
    u16* Wh = (u16*)ws;                        // 3 x 2 MB
    u16* Wm = Wh + (1u << 20);
    u16* Wl = Wm + (1u << 20);
    u16* Rbase = (u16*)(ws + 6u * 1024 * 1024);  // 2 bufs x 3 levels x 1 MB

    auto Rp = [&](int bf, int lv) { return Rbase + ((size_t)bf * 3 + lv) * (Vv * Ff); };

    wsplit_kernel<<<4096, 256, 0, stream>>>(W, Wh, Wm, Wl);
    init_kernel<<<2048, 256, 0, stream>>>(X, b, Rp(0, 0), Rp(0, 1), Rp(0, 2));

    for (int t = 1; t <= 126; ++t) {
        int src = (t - 1) & 1, dst = t & 1;
        step_kernel<<<256, 256, 0, stream>>>(Rp(src, 0), Rp(src, 1), Rp(src, 2),
                                             Wh, Wm, Wl,
                                             Rp(dst, 0), Rp(dst, 1), Rp(dst, 2),
                                             b, X + (size_t)t * Vv);
    }

    diag_kernel<<<512, 64, 0, stream>>>(Rp(0, 0), Rp(0, 1), Rp(0, 2), W, b, out);
}

// Round 4
// 2785.490 us; speedup vs baseline: 3.3808x; 1.1335x over previous
//
#include <hip/hip_runtime.h>
#include <stdint.h>

#define Vv 512
#define Ff 1024

typedef unsigned short u16;
typedef __attribute__((ext_vector_type(8))) short s16x8;
typedef __attribute__((ext_vector_type(4))) float f32x4;

// Exact 3-way bf16 truncation split: v == h + m + l (bit-exact, 24 mantissa bits)
__device__ __forceinline__ void split3(float v, u16& h, u16& m, u16& l) {
    unsigned u = __float_as_uint(v);
    float fh = __uint_as_float(u & 0xFFFF0000u);
    h = (u16)(u >> 16);
    float r1 = v - fh;                         // exact
    unsigned u1 = __float_as_uint(r1);
    float fm = __uint_as_float(u1 & 0xFFFF0000u);
    m = (u16)(u1 >> 16);
    float r2 = r1 - fm;                        // exact
    l = (u16)(__float_as_uint(r2) >> 16);
}

__global__ void wsplit_kernel(const float* __restrict__ W,
                              u16* __restrict__ Wh, u16* __restrict__ Wm, u16* __restrict__ Wl) {
    int idx = blockIdx.x * 256 + threadIdx.x;
    float w = W[idx];
    u16 h, m, l; split3(w, h, m, l);
    Wh[idx] = h; Wm[idx] = m; Wl[idx] = l;
}

__global__ void init_kernel(const float* __restrict__ X, const float* __restrict__ b,
                            u16* __restrict__ Rh, u16* __restrict__ Rm, u16* __restrict__ Rl) {
    int idx = blockIdx.x * 256 + threadIdx.x;
    int i = idx >> 10, j = idx & 1023;
    float u = b[j];
    if (j < Vv && i != j) u = 0.5f * u + 0.5f * X[j];
    u = fmaxf(u, 0.f);
    u16 h, m, l; split3(u, h, m, l);
    Rh[idx] = h; Rm[idx] = m; Rl[idx] = l;
}

// One step. Tile 32x64/block, 256 blocks, 8 waves; waves split K (wave w: K-slice
// kq = w&3 of each BK=128 chunk; nh = w>>2 picks 32-col half). 6-product bf16x3.
// LDS: dbuf x (A: 3lv x 32r x 128k @ lv*8192 ; B: 3lv x 64r x 128k @ 24576+lv*16384),
// 16B units, k-octet-major: unit L = s*R + slot, slot = row ^ (s&7)  (bank swizzle,
// applied as inverse-permuted GLOBAL source + swizzled READ; LDS dest stays linear).
__global__ __launch_bounds__(512, 1)
void step_kernel(const u16* __restrict__ Rh, const u16* __restrict__ Rm, const u16* __restrict__ Rl,
                 const u16* __restrict__ Wh, const u16* __restrict__ Wm, const u16* __restrict__ Wl,
                 u16* __restrict__ Oh, u16* __restrict__ Om, u16* __restrict__ Ol,
                 const float* __restrict__ b, const float* __restrict__ x) {
    __shared__ unsigned char smem[2 * 73728];   // 144 KB

    const int tid = threadIdx.x;
    const int bid = blockIdx.x;
    const int rb = (bid & 7) * 32 + (bid >> 3);   // XCD-chunked swizzle (bijective)
    const int i0 = (rb & 15) * 32;
    const int j0 = (rb >> 4) * 64;

    // staging: 4608 16B-units per chunk (A 1536 + B 3072) -> 9 per thread
    const u16* gb[9]; unsigned lo[9];
    {
        const u16* Rlv[3] = {Rh, Rm, Rl};
        const u16* Wlv[3] = {Wh, Wm, Wl};
#pragma unroll
        for (int q = 0; q < 9; ++q) {
            int G = q * 512 + tid;
            if (G < 1536) {                        // A region
                int lv = G >> 9, L = G & 511, s = L >> 5, rs = L & 31;
                int r = rs ^ (s & 7);              // inverse-permuted source row
                gb[q] = Rlv[lv] + (size_t)(i0 + r) * Ff + s * 8;
                lo[q] = (unsigned)(lv * 8192 + L * 16);
            } else {                               // B region
                int Gp = G - 1536;
                int lv = Gp >> 10, L = Gp & 1023, s = L >> 6, rs = L & 63;
                int r = rs ^ (s & 7);
                gb[q] = Wlv[lv] + (size_t)(j0 + r) * Ff + s * 8;
                lo[q] = (unsigned)(24576 + lv * 16384 + L * 16);
            }
        }
    }

    const int lane = tid & 63, l15 = lane & 15, l4 = lane >> 4;
    const int w = tid >> 6, kq = w & 3, nh = w >> 2;
    const int sA = kq * 4 + l4, sx = sA & 7;

    unsigned aoff[2], boff[2];
#pragma unroll
    for (int mf = 0; mf < 2; ++mf)
        aoff[mf] = (unsigned)((sA * 32 + ((mf * 16 + l15) ^ sx)) * 16);
#pragma unroll
    for (int nf = 0; nf < 2; ++nf)
        boff[nf] = (unsigned)(24576 + (sA * 64 + ((nh * 32 + nf * 16 + l15) ^ sx)) * 16);

    f32x4 acc[2][2];
#pragma unroll
    for (int a = 0; a < 2; ++a)
#pragma unroll
        for (int c = 0; c < 2; ++c) acc[a][c] = (f32x4){0.f, 0.f, 0.f, 0.f};

#define STAGE(buf, kb) do {                                                           \
        unsigned bofs_ = (unsigned)(buf) * 73728u;                                    \
        _Pragma("unroll")                                                             \
        for (int q_ = 0; q_ < 9; ++q_)                                                \
            __builtin_amdgcn_global_load_lds(                                         \
                (const __attribute__((address_space(1))) void*)(gb[q_] + (kb) * 128), \
                (__attribute__((address_space(3))) void*)(smem + bofs_ + lo[q_]),     \
                16, 0, 0);                                                            \
    } while (0)

    STAGE(0, 0);
    __syncthreads();

    for (int kb = 0; kb < 8; ++kb) {
        const unsigned cb = (unsigned)(kb & 1) * 73728u;
        if (kb < 7) STAGE((kb & 1) ^ 1, kb + 1);   // async prefetch under compute

        s16x8 Af[3][2], Bf[3][2];
#pragma unroll
        for (int lv = 0; lv < 3; ++lv) {
#pragma unroll
            for (int mf = 0; mf < 2; ++mf)
                Af[lv][mf] = *(const s16x8*)(smem + cb + (unsigned)(lv * 8192) + aoff[mf]);
#pragma unroll
            for (int nf = 0; nf < 2; ++nf)
                Bf[lv][nf] = *(const s16x8*)(smem + cb + (unsigned)(lv * 16384) + boff[nf]);
        }

        const int LVA[6] = {0, 0, 1, 0, 2, 1};
        const int LVB[6] = {0, 1, 0, 2, 0, 1};
#pragma unroll
        for (int p = 0; p < 6; ++p)
#pragma unroll
            for (int mf = 0; mf < 2; ++mf)
#pragma unroll
                for (int nf = 0; nf < 2; ++nf)
                    asm("v_mfma_f32_16x16x32_bf16 %0, %1, %2, %0"
                        : "+v"(acc[mf][nf])
                        : "v"(Af[LVA[p]][mf]), "v"(Bf[LVB[p]][nf]));

        __syncthreads();
    }
#undef STAGE

    asm volatile("s_nop 7\n\ts_nop 7");   // MFMA->VALU read hazard guard

    // Cross-wave K reduction: each wave dumps its 32x32 partial (fp32) to LDS.
    float* red = (float*)smem;   // 8 waves x 1024 f32 = 32 KB
#pragma unroll
    for (int mf = 0; mf < 2; ++mf)
#pragma unroll
        for (int nf = 0; nf < 2; ++nf)
#pragma unroll
            for (int r = 0; r < 4; ++r) {
                int row = mf * 16 + l4 * 4 + r;     // C layout: col=lane&15, row=(lane>>4)*4+reg
                int cl  = nf * 16 + l15;
                red[w * 1024 + row * 32 + cl] = acc[mf][nf][r];
            }
    __syncthreads();

    // 512 threads x 4 outputs: sum 4 K-partials, bias+mask+relu+split, store.
    const int o = tid * 4;
    const int i_loc = o >> 6, jb4 = o & 63;
    const int i = i0 + i_loc;
    const float4 b4 = *(const float4*)(b + j0 + jb4);
    float xv[4] = {0.f, 0.f, 0.f, 0.f};
    if (j0 < Vv) *(float4*)xv = *(const float4*)(x + j0 + jb4);
    const float bb[4] = {b4.x, b4.y, b4.z, b4.w};
    u16 oh[4], om[4], ol[4];
#pragma unroll
    for (int e = 0; e < 4; ++e) {
        int j_loc = jb4 + e;
        int nho = j_loc >> 5, cl = j_loc & 31;
        int base = i_loc * 32 + cl;
        float v = red[(nho * 4 + 0) * 1024 + base]
                + red[(nho * 4 + 1) * 1024 + base]
                + red[(nho * 4 + 2) * 1024 + base]
                + red[(nho * 4 + 3) * 1024 + base];
        float u = v + bb[e];
        int j = j0 + j_loc;
        if (j < Vv && i != j) u = 0.5f * u + 0.5f * xv[e];
        u = fmaxf(u, 0.f);
        split3(u, oh[e], om[e], ol[e]);
    }
    size_t ob = (size_t)i * Ff + j0 + jb4;
    *(ushort4*)(Oh + ob) = *(ushort4*)oh;
    *(ushort4*)(Om + ob) = *(ushort4*)om;
    *(ushort4*)(Ol + ob) = *(ushort4*)ol;
}

// Final: out[i] = dot(R126[i,:], W[i,:]) + b[i]; R reconstructed exactly (h+m+l).
__global__ void diag_kernel(const u16* __restrict__ Rh, const u16* __restrict__ Rm,
                            const u16* __restrict__ Rl,
                            const float* __restrict__ W, const float* __restrict__ b,
                            float* __restrict__ out) {
    int i = blockIdx.x;
    int lane = threadIdx.x;
    float s = 0.f;
    for (int c = lane; c < Ff; c += 64) {
        size_t o = (size_t)i * Ff + c;
        float r = __uint_as_float((unsigned)Rh[o] << 16)
                + __uint_as_float((unsigned)Rm[o] << 16)
                + __uint_as_float((unsigned)Rl[o] << 16);
        s += r * W[o];
    }
#pragma unroll
    for (int off = 32; off > 0; off >>= 1) s += __shfl_down(s, off);
    if (lane == 0) out[i] = s + b[i];
}

extern "C" void kernel_launch(void* const* d_in, const int* in_sizes, int n_in,
                              void* d_out, int out_size, void* d_ws, size_t ws_size,
                              hipStream_t stream) {
    const float* X = (const float*)d_in[0];   // (128, 512)
    const float* W = (const float*)d_in[1];   // (1024, 1024)
    const float* b = (const float*)d_in[2];   // (1024,)
    float* out = (float*)d_out;

    char* ws = (char*)d_ws;
    u16* Wh = (u16*)ws;                          // 3 x 2 MB
    u16* Wm = Wh + (1u << 20);
    u16* Wl = Wm + (1u << 20);
    u16* Rbase = (u16*)(ws + 6u * 1024 * 1024);  // 2 bufs x 3 levels x 1 MB

    auto Rp = [&](int bf, int lv) { return Rbase + ((size_t)bf * 3 + lv) * (Vv * Ff); };

    wsplit_kernel<<<4096, 256, 0, stream>>>(W, Wh, Wm, Wl);
    init_kernel<<<2048, 256, 0, stream>>>(X, b, Rp(0, 0), Rp(0, 1), Rp(0, 2));

    for (int t = 1; t <= 126; ++t) {
        int src = (t - 1) & 1, dst = t & 1;
        step_kernel<<<256, 512, 0, stream>>>(Rp(src, 0), Rp(src, 1), Rp(src, 2),
                                             Wh, Wm, Wl,
                                             Rp(dst, 0), Rp(dst, 1), Rp(dst, 2),
                                             b, X + (size_t)t * Vv);
    }

    diag_kernel<<<512, 64, 0, stream>>>(Rp(0, 0), Rp(0, 1), Rp(0, 2), W, b, out);
}

// Round 5
// 1415.281 us; speedup vs baseline: 6.6539x; 1.9682x over previous
//
#include <hip/hip_runtime.h>
#include <stdint.h>

#define Vv 512
#define Ff 1024

typedef unsigned short u16;
typedef __attribute__((ext_vector_type(8))) short s16x8;
typedef __attribute__((ext_vector_type(4))) float f32x4;

// Exact 3-way bf16 truncation split: v == h + m + l (bit-exact, 24 mantissa bits)
__device__ __forceinline__ void split3(float v, u16& h, u16& m, u16& l) {
    unsigned u = __float_as_uint(v);
    float fh = __uint_as_float(u & 0xFFFF0000u);
    h = (u16)(u >> 16);
    float r1 = v - fh;                         // exact
    unsigned u1 = __float_as_uint(r1);
    float fm = __uint_as_float(u1 & 0xFFFF0000u);
    m = (u16)(u1 >> 16);
    float r2 = r1 - fm;                        // exact
    l = (u16)(__float_as_uint(r2) >> 16);
}

__global__ void wsplit_kernel(const float* __restrict__ W,
                              u16* __restrict__ Wh, u16* __restrict__ Wm, u16* __restrict__ Wl) {
    int idx = blockIdx.x * 256 + threadIdx.x;
    float w = W[idx];
    u16 h, m, l; split3(w, h, m, l);
    Wh[idx] = h; Wm[idx] = m; Wl[idx] = l;
}

__global__ void init_kernel(const float* __restrict__ X, const float* __restrict__ b,
                            u16* __restrict__ Rh, u16* __restrict__ Rm, u16* __restrict__ Rl) {
    int idx = blockIdx.x * 256 + threadIdx.x;
    int i = idx >> 10, j = idx & 1023;
    float u = b[j];
    if (j < Vv && i != j) u = 0.5f * u + 0.5f * X[j];
    u = fmaxf(u, 0.f);
    u16 h, m, l; split3(u, h, m, l);
    Rh[idx] = h; Rm[idx] = m; Rl[idx] = l;
}

// One step. Tile 32x64/block, 256 blocks, 8 waves; waves split K (wave w: K-slice
// kq = w&3 of each BK=128 chunk; nh = w>>2 picks the 32-col half). 6-product bf16x3.
// LDS layout per buffer: A: lv*8192, 32 rows x 16 slots; B: 24576 + lv*16384,
// 64 rows x 16 slots. 16B units, ROW-major: unit u = row*16 + (slot ^ (row&7)).
// -> global_load_lds waves read 4 rows x 256B contiguous (coalesced, 16 lines);
//    the XOR is a within-256B permutation applied to BOTH source and read (rule 21).
__global__ __launch_bounds__(512, 1)
void step_kernel(const u16* __restrict__ Rh, const u16* __restrict__ Rm, const u16* __restrict__ Rl,
                 const u16* __restrict__ Wh, const u16* __restrict__ Wm, const u16* __restrict__ Wl,
                 u16* __restrict__ Oh, u16* __restrict__ Om, u16* __restrict__ Ol,
                 const float* __restrict__ b, const float* __restrict__ x) {
    __shared__ unsigned char smem[2 * 73728];   // 144 KB

    const int tid = threadIdx.x;
    const int bid = blockIdx.x;
    const int rb = (bid & 7) * 32 + (bid >> 3);   // XCD-chunked swizzle (bijective)
    const int i0 = (rb & 15) * 32;
    const int j0 = (rb >> 4) * 64;

    // staging: 4608 16B-units per chunk (A 1536 + B 3072) -> 9 per thread
    const u16* gb[9]; unsigned lo[9];
    {
        const u16* Rlv[3] = {Rh, Rm, Rl};
        const u16* Wlv[3] = {Wh, Wm, Wl};
#pragma unroll
        for (int q = 0; q < 9; ++q) {
            int G = q * 512 + tid;
            if (G < 1536) {                        // A region: 3 levels x 512 units
                int lv = G >> 9, L = G & 511, r = L >> 4, ssw = L & 15;
                int s = ssw ^ (r & 7);             // inverse-permuted source slot
                gb[q] = Rlv[lv] + (size_t)(i0 + r) * Ff + s * 8;
                lo[q] = (unsigned)(lv * 8192 + L * 16);
            } else {                               // B region: 3 levels x 1024 units
                int Gp = G - 1536;
                int lv = Gp >> 10, L = Gp & 1023, r = L >> 4, ssw = L & 15;
                int s = ssw ^ (r & 7);
                gb[q] = Wlv[lv] + (size_t)(j0 + r) * Ff + s * 8;
                lo[q] = (unsigned)(24576 + lv * 16384 + L * 16);
            }
        }
    }

    const int lane = tid & 63, l15 = lane & 15, l4 = lane >> 4;
    const int w = tid >> 6, kq = w & 3, nh = w >> 2;
    const int ssw = (kq * 4 + l4) ^ (l15 & 7);     // swizzled slot, same for A and B

    unsigned aoff[2], boff[2];
#pragma unroll
    for (int mf = 0; mf < 2; ++mf)
        aoff[mf] = (unsigned)(((mf * 16 + l15) * 16 + ssw) * 16);
#pragma unroll
    for (int nf = 0; nf < 2; ++nf)
        boff[nf] = (unsigned)(24576 + ((nh * 32 + nf * 16 + l15) * 16 + ssw) * 16);

    f32x4 acc[2][2];
#pragma unroll
    for (int a = 0; a < 2; ++a)
#pragma unroll
        for (int c = 0; c < 2; ++c) acc[a][c] = (f32x4){0.f, 0.f, 0.f, 0.f};

#define STAGE(buf, kb) do {                                                           \
        unsigned bofs_ = (unsigned)(buf) * 73728u;                                    \
        _Pragma("unroll")                                                             \
        for (int q_ = 0; q_ < 9; ++q_)                                                \
            __builtin_amdgcn_global_load_lds(                                         \
                (const __attribute__((address_space(1))) void*)(gb[q_] + (kb) * 128), \
                (__attribute__((address_space(3))) void*)(smem + bofs_ + lo[q_]),     \
                16, 0, 0);                                                            \
    } while (0)

    STAGE(0, 0);
    __syncthreads();

    for (int kb = 0; kb < 8; ++kb) {
        const unsigned cb = (unsigned)(kb & 1) * 73728u;
        if (kb < 7) STAGE((kb & 1) ^ 1, kb + 1);   // async prefetch under compute

        s16x8 Af[3][2], Bf[3][2];
#pragma unroll
        for (int lv = 0; lv < 3; ++lv) {
#pragma unroll
            for (int mf = 0; mf < 2; ++mf)
                Af[lv][mf] = *(const s16x8*)(smem + cb + (unsigned)(lv * 8192) + aoff[mf]);
#pragma unroll
            for (int nf = 0; nf < 2; ++nf)
                Bf[lv][nf] = *(const s16x8*)(smem + cb + (unsigned)(lv * 16384) + boff[nf]);
        }

        const int LVA[6] = {0, 0, 1, 0, 2, 1};
        const int LVB[6] = {0, 1, 0, 2, 0, 1};
        __builtin_amdgcn_s_setprio(1);
#pragma unroll
        for (int p = 0; p < 6; ++p)
#pragma unroll
            for (int mf = 0; mf < 2; ++mf)
#pragma unroll
                for (int nf = 0; nf < 2; ++nf)
                    asm("v_mfma_f32_16x16x32_bf16 %0, %1, %2, %0"
                        : "+v"(acc[mf][nf])
                        : "v"(Af[LVA[p]][mf]), "v"(Bf[LVB[p]][nf]));
        __builtin_amdgcn_s_setprio(0);

        __syncthreads();
    }
#undef STAGE

    asm volatile("s_nop 7\n\ts_nop 7");   // MFMA->VALU read hazard guard

    // Cross-wave K reduction: each wave dumps its 32x32 partial (fp32) to LDS.
    float* red = (float*)smem;   // 8 waves x 1024 f32 = 32 KB
#pragma unroll
    for (int mf = 0; mf < 2; ++mf)
#pragma unroll
        for (int nf = 0; nf < 2; ++nf)
#pragma unroll
            for (int r = 0; r < 4; ++r) {
                int row = mf * 16 + l4 * 4 + r;     // C layout: col=lane&15, row=(lane>>4)*4+reg
                int cl  = nf * 16 + l15;
                red[w * 1024 + row * 32 + cl] = acc[mf][nf][r];
            }
    __syncthreads();

    // 512 threads x 4 outputs: sum 4 K-partials, bias+mask+relu+split, store.
    const int o = tid * 4;
    const int i_loc = o >> 6, jb4 = o & 63;
    const int i = i0 + i_loc;
    const float4 b4 = *(const float4*)(b + j0 + jb4);
    float xv[4] = {0.f, 0.f, 0.f, 0.f};
    if (j0 < Vv) *(float4*)xv = *(const float4*)(x + j0 + jb4);
    const float bb[4] = {b4.x, b4.y, b4.z, b4.w};
    u16 oh[4], om[4], ol[4];
#pragma unroll
    for (int e = 0; e < 4; ++e) {
        int j_loc = jb4 + e;
        int nho = j_loc >> 5, cl = j_loc & 31;
        int base = i_loc * 32 + cl;
        float v = red[(nho * 4 + 0) * 1024 + base]
                + red[(nho * 4 + 1) * 1024 + base]
                + red[(nho * 4 + 2) * 1024 + base]
                + red[(nho * 4 + 3) * 1024 + base];
        float u = v + bb[e];
        int j = j0 + j_loc;
        if (j < Vv && i != j) u = 0.5f * u + 0.5f * xv[e];
        u = fmaxf(u, 0.f);
        split3(u, oh[e], om[e], ol[e]);
    }
    size_t ob = (size_t)i * Ff + j0 + jb4;
    *(ushort4*)(Oh + ob) = *(ushort4*)oh;
    *(ushort4*)(Om + ob) = *(ushort4*)om;
    *(ushort4*)(Ol + ob) = *(ushort4*)ol;
}

// Final: out[i] = dot(R126[i,:], W[i,:]) + b[i]; R reconstructed exactly (h+m+l).
__global__ void diag_kernel(const u16* __restrict__ Rh, const u16* __restrict__ Rm,
                            const u16* __restrict__ Rl,
                            const float* __restrict__ W, const float* __restrict__ b,
                            float* __restrict__ out) {
    int i = blockIdx.x;
    int lane = threadIdx.x;
    float s = 0.f;
    for (int c = lane; c < Ff; c += 64) {
        size_t o = (size_t)i * Ff + c;
        float r = __uint_as_float((unsigned)Rh[o] << 16)
                + __uint_as_float((unsigned)Rm[o] << 16)
                + __uint_as_float((unsigned)Rl[o] << 16);
        s += r * W[o];
    }
#pragma unroll
    for (int off = 32; off > 0; off >>= 1) s += __shfl_down(s, off);
    if (lane == 0) out[i] = s + b[i];
}

extern "C" void kernel_launch(void* const* d_in, const int* in_sizes, int n_in,
                              void* d_out, int out_size, void* d_ws, size_t ws_size,
                              hipStream_t stream) {
    const float* X = (const float*)d_in[0];   // (128, 512)
    const float* W = (const float*)d_in[1];   // (1024, 1024)
    const float* b = (const float*)d_in[2];   // (1024,)
    float* out = (float*)d_out;

    char* ws = (char*)d_ws;
    u16* Wh = (u16*)ws;                          // 3 x 2 MB
    u16* Wm = Wh + (1u << 20);
    u16* Wl = Wm + (1u << 20);
    u16* Rbase = (u16*)(ws + 6u * 1024 * 1024);  // 2 bufs x 3 levels x 1 MB

    auto Rp = [&](int bf, int lv) { return Rbase + ((size_t)bf * 3 + lv) * (Vv * Ff); };

    wsplit_kernel<<<4096, 256, 0, stream>>>(W, Wh, Wm, Wl);
    init_kernel<<<2048, 256, 0, stream>>>(X, b, Rp(0, 0), Rp(0, 1), Rp(0, 2));

    for (int t = 1; t <= 126; ++t) {
        int src = (t - 1) & 1, dst = t & 1;
        step_kernel<<<256, 512, 0, stream>>>(Rp(src, 0), Rp(src, 1), Rp(src, 2),
                                             Wh, Wm, Wl,
                                             Rp(dst, 0), Rp(dst, 1), Rp(dst, 2),
                                             b, X + (size_t)t * Vv);
    }

    diag_kernel<<<512, 64, 0, stream>>>(Rp(0, 0), Rp(0, 1), Rp(0, 2), W, b, out);
}